// Round 1
// baseline (200.486 us; speedup 1.0000x reference)
//
#include <hip/hip_runtime.h>
#include <math.h>

#define N_NODES 10000
#define N_EDGES 320000
#define IN_FEATS 256
#define N_HEADS 4
#define N_UNITS 64
#define OUT_FEATS 47
#define NEG_SLOPE 0.2f
#define GB2 157  // gemm2 tile blocks: (N_NODES+63)/64

typedef __attribute__((ext_vector_type(8))) short bf16x8;
typedef __attribute__((ext_vector_type(4))) float f32x4;

__device__ __forceinline__ float wave_reduce_sum(float v) {
#pragma unroll
  for (int s = 32; s > 0; s >>= 1) v += __shfl_down(v, s, 64);
  return __shfl(v, 0, 64);
}
__device__ __forceinline__ float wave_reduce_max(float v) {
#pragma unroll
  for (int s = 32; s > 0; s >>= 1) v = fmaxf(v, __shfl_down(v, s, 64));
  return __shfl(v, 0, 64);
}

__device__ __forceinline__ float lrelu_exp(float s) {
  s = (s > 0.f) ? s : NEG_SLOPE * s;
  return expf(s);
}

// fp32 -> bf16 round-to-nearest-even
__device__ __forceinline__ unsigned f2bf(float f) {
  unsigned u = __float_as_uint(f);
  return (u + 0x7FFFu + ((u >> 16) & 1u)) >> 16;
}

// ---------------- fused prep: deg count + W1/W2 packing + wa/wb ----------------
__global__ __launch_bounds__(256) void prep_kernel(
    const int* __restrict__ dst, int* __restrict__ deg,
    const float* __restrict__ W1, unsigned short* __restrict__ W1f,
    const float* __restrict__ W2, unsigned short* __restrict__ W2f,
    const float* __restrict__ al2, const float* __restrict__ ar2,
    float* __restrict__ wa, float* __restrict__ wb) {
  int b = blockIdx.x;
  int t = threadIdx.x;
  if (b < 1250) {
    int e = b * 256 + t;
    if (e < N_EDGES) atomicAdd(&deg[dst[e]], 1);
  } else if (b < 1250 + 256) {
    int o = (b - 1250) * 256 + t;  // 0..65535
    int j = o & 7;
    int lane = (o >> 3) & 63;
    int r = o >> 9;
    int ks = r & 7;
    int ntg = r >> 3;
    int k = ks * 32 + (lane >> 4) * 8 + j;
    int n = ntg * 16 + (lane & 15);
    W1f[o] = (unsigned short)f2bf(W1[k * 256 + n]);
  } else if (b < 1554) {
    int o = (b - 1506) * 256 + t;  // 0..12287
    int j = o & 7;
    int lane = (o >> 3) & 63;
    int r = o >> 9;  // 0..23
    int ks = r & 7;
    int ntg = r >> 3;  // 0..2
    int k = ks * 32 + (lane >> 4) * 8 + j;
    int n = ntg * 16 + (lane & 15);
    W2f[o] = (n < OUT_FEATS) ? (unsigned short)f2bf(W2[k * OUT_FEATS + n]) : 0;
  } else {
    float a = 0.f, r = 0.f;
    for (int c = 0; c < OUT_FEATS; ++c) {
      float w = W2[t * OUT_FEATS + c];
      a += w * al2[c];
      r += w * ar2[c];
    }
    wa[t] = a;
    wb[t] = r;
  }
}

// CSR fill: src/dst ids + layer-1 exp-scores (edge-parallel — full MLP, removes
// the dependent src->el1->exp chain from agg1's per-block critical path).
__global__ void fill_kernel(const int* __restrict__ src, const int* __restrict__ dst,
                            int* __restrict__ cursor, int* __restrict__ src_csr,
                            int* __restrict__ dst_csr, const float* __restrict__ el1,
                            const float* __restrict__ er1, float* __restrict__ score1) {
  int e = blockIdx.x * blockDim.x + threadIdx.x;
  if (e >= N_EDGES) return;
  int s = src[e];
  int d = dst[e];
  int p = atomicAdd(&cursor[d], 1);
  src_csr[p] = s;
  dst_csr[p] = d;
  float4 el = ((const float4*)el1)[s];
  float4 er = ((const float4*)er1)[d];
  ((float4*)score1)[p] =
      make_float4(lrelu_exp(el.x + er.x), lrelu_exp(el.y + er.y),
                  lrelu_exp(el.z + er.z), lrelu_exp(el.w + er.w));
}

// ---------------- Layer 1 GEMM (MFMA bf16) + fused scan (block 313) ----------------
__global__ __launch_bounds__(256) void gemm1_scan_kernel(
    const float* __restrict__ features, const unsigned short* __restrict__ W1f,
    const float* __restrict__ al1, const float* __restrict__ ar1,
    unsigned short* __restrict__ feat1h, float* __restrict__ el1, float* __restrict__ er1,
    const int* __restrict__ deg, int* __restrict__ offsets, int* __restrict__ cursor) {
  __shared__ __align__(16) char smem[49152];
  int t = threadIdx.x;

  if (blockIdx.x == 313) {  // ---- scan path ----
    int* partial = (int*)smem;
    const int chunk = (N_NODES + 255) / 256;  // 40
    int start = t * chunk;
    int end = min(start + chunk, N_NODES);
    int sum = 0;
    for (int i = start; i < end; ++i) sum += deg[i];
    partial[t] = sum;
    __syncthreads();
    for (int s = 1; s < 256; s <<= 1) {
      int v = (t >= s) ? partial[t - s] : 0;
      __syncthreads();
      partial[t] += v;
      __syncthreads();
    }
    int base = (t == 0) ? 0 : partial[t - 1];
    for (int i = start; i < end; ++i) {
      offsets[i] = base;
      cursor[i] = base;
      base += deg[i];
    }
    if (t == 0) offsets[N_NODES] = partial[255];
    return;
  }

  // ---- GEMM path ----
  unsigned short* ldsA = (unsigned short*)smem;                    // 16 KB
  unsigned short* ldsBbuf[2] = {(unsigned short*)(smem + 16384),
                                (unsigned short*)(smem + 32768)};  // 2 x 16 KB
  float* ldsC = (float*)(smem + 16384);                            // 32 KB (reuse B)

  int n0 = blockIdx.x * 32;
  int lane = t & 63;
  int w = t >> 6;
  int quad = lane >> 4;

  const float4* feat4 = (const float4*)features;
#pragma unroll
  for (int i = 0; i < 8; ++i) {
    int idx = i * 256 + t;
    int m = idx >> 6;
    int kb4 = idx & 63;
    float4 f = make_float4(0.f, 0.f, 0.f, 0.f);
    if (n0 + m < N_NODES) f = feat4[(size_t)(n0 + m) * 64 + kb4];
    unsigned u0 = f2bf(f.x) | (f2bf(f.y) << 16);
    unsigned u1 = f2bf(f.z) | (f2bf(f.w) << 16);
    int kb = kb4 >> 1;
    int di = m * 256 + ((kb ^ (m & 7)) << 3) + ((kb4 & 1) << 2);
    *(uint2*)&ldsA[di] = make_uint2(u0, u1);
  }

  const uint4* W1f4 = (const uint4*)W1f;
  uint4 pb[4];
#pragma unroll
  for (int it = 0; it < 4; ++it) {
    int ci = it * 256 + t;
    pb[it] = W1f4[((ci >> 6) * 8 + 0) * 64 + (ci & 63)];
  }
#pragma unroll
  for (int it = 0; it < 4; ++it) ((uint4*)ldsBbuf[0])[it * 256 + t] = pb[it];
  __syncthreads();

  f32x4 acc[2][4];
#pragma unroll
  for (int mt = 0; mt < 2; ++mt)
#pragma unroll
    for (int nt = 0; nt < 4; ++nt) acc[mt][nt] = 0.f;

  for (int ks = 0; ks < 8; ++ks) {
    if (ks < 7) {
#pragma unroll
      for (int it = 0; it < 4; ++it) {
        int ci = it * 256 + t;
        pb[it] = W1f4[((ci >> 6) * 8 + ks + 1) * 64 + (ci & 63)];
      }
    }
    unsigned short* B = ldsBbuf[ks & 1];
    bf16x8 af[2];
#pragma unroll
    for (int mt = 0; mt < 2; ++mt) {
      int m = mt * 16 + (lane & 15);
      int kb = ks * 4 + quad;
      af[mt] = *(const bf16x8*)&ldsA[m * 256 + ((kb ^ (m & 7)) << 3)];
    }
#pragma unroll
    for (int nt = 0; nt < 4; ++nt) {
      bf16x8 bf = *(const bf16x8*)&B[((w * 4 + nt) * 64 + lane) * 8];
#pragma unroll
      for (int mt = 0; mt < 2; ++mt)
        acc[mt][nt] = __builtin_amdgcn_mfma_f32_16x16x32_bf16(af[mt], bf, acc[mt][nt], 0, 0, 0);
    }
    if (ks < 7) {
      unsigned short* Bn = ldsBbuf[(ks + 1) & 1];
#pragma unroll
      for (int it = 0; it < 4; ++it) ((uint4*)Bn)[it * 256 + t] = pb[it];
    }
    __syncthreads();
  }

#pragma unroll
  for (int mt = 0; mt < 2; ++mt)
#pragma unroll
    for (int nt = 0; nt < 4; ++nt)
#pragma unroll
      for (int r = 0; r < 4; ++r)
        ldsC[(mt * 16 + quad * 4 + r) * 256 + w * 64 + nt * 16 + (lane & 15)] = acc[mt][nt][r];
  __syncthreads();

  int c = lane * 4;
  int r0 = w * 8;
  float4 alv = ((const float4*)al1)[lane];
  float4 arv = ((const float4*)ar1)[lane];
#pragma unroll
  for (int i = 0; i < 8; ++i) {
    int rl = r0 + i;
    int row = n0 + rl;
    float4 a = *(const float4*)&ldsC[rl * 256 + c];
    bool valid = row < N_NODES;
    if (valid) {
      unsigned p0 = f2bf(a.x) | (f2bf(a.y) << 16);
      unsigned p1 = f2bf(a.z) | (f2bf(a.w) << 16);
      *(uint2*)&feat1h[(size_t)row * 256 + c] = make_uint2(p0, p1);
    }
    float el = a.x * alv.x + a.y * alv.y + a.z * alv.z + a.w * alv.w;
    float er = a.x * arv.x + a.y * arv.y + a.z * arv.z + a.w * arv.w;
#pragma unroll
    for (int s = 8; s > 0; s >>= 1) {
      el += __shfl_down(el, s, 16);
      er += __shfl_down(er, s, 16);
    }
    if ((lane & 15) == 0 && valid) {
      el1[row * 4 + (lane >> 4)] = el;
      er1[row * 4 + (lane >> 4)] = er;
    }
  }
}

// ---------------- Layer 1 aggregate: streaming scores + bf16 gather ----------------
// Phase A streams src ids + precomputed exp-scores into per-head LDS planes and
// accumulates the softmax denominator (one add per edge, not 32x redundant).
// Phase B: half-wave per edge, 2 edges unrolled per iteration for 2x MLP.
__global__ __launch_bounds__(256) void agg1_kernel(
    const int* __restrict__ src_csr, const int* __restrict__ offsets,
    const unsigned short* __restrict__ feat1h, const float* __restrict__ score1,
    const float* __restrict__ wa, const float* __restrict__ wb,
    unsigned short* __restrict__ h2h, float* __restrict__ el2, float* __restrict__ er2) {
  __shared__ float lds_sh[4][256];
  __shared__ int lds_sn[256];
  __shared__ float ldsacc[4][256];
  __shared__ float ldssum[4][4];
  __shared__ float ldse[4], ldsr[4];
  int n = blockIdx.x;
  int t = threadIdx.x;
  int w = t >> 6;
  int lane = t & 63;
  int half = lane >> 5;
  int hl = lane & 31;
  int off = offsets[n];
  int deg = offsets[n + 1] - off;
  int head = hl >> 3;

  float acc[8];
#pragma unroll
  for (int r = 0; r < 8; ++r) acc[r] = 0.f;
  float4 es4 = {0.f, 0.f, 0.f, 0.f};

  for (int c0 = 0; c0 < deg; c0 += 256) {
    int cnt = min(256, deg - c0);
    if (t < cnt) {
      lds_sn[t] = src_csr[off + c0 + t];
      float4 s4 = ((const float4*)score1)[off + c0 + t];
      lds_sh[0][t] = s4.x;
      lds_sh[1][t] = s4.y;
      lds_sh[2][t] = s4.z;
      lds_sh[3][t] = s4.w;
      es4.x += s4.x;
      es4.y += s4.y;
      es4.z += s4.z;
      es4.w += s4.w;
    }
    __syncthreads();
    int p = w * 2 + half;
    for (; p + 8 < cnt; p += 16) {
      int sn0 = lds_sn[p];
      int sn1 = lds_sn[p + 8];
      float aw0 = lds_sh[head][p];
      float aw1 = lds_sh[head][p + 8];
      uint4 u0 = *(const uint4*)&feat1h[(size_t)sn0 * 256 + hl * 8];
      uint4 u1 = *(const uint4*)&feat1h[(size_t)sn1 * 256 + hl * 8];
      acc[0] += aw0 * __uint_as_float(u0.x << 16);
      acc[1] += aw0 * __uint_as_float(u0.x & 0xFFFF0000u);
      acc[2] += aw0 * __uint_as_float(u0.y << 16);
      acc[3] += aw0 * __uint_as_float(u0.y & 0xFFFF0000u);
      acc[4] += aw0 * __uint_as_float(u0.z << 16);
      acc[5] += aw0 * __uint_as_float(u0.z & 0xFFFF0000u);
      acc[6] += aw0 * __uint_as_float(u0.w << 16);
      acc[7] += aw0 * __uint_as_float(u0.w & 0xFFFF0000u);
      acc[0] += aw1 * __uint_as_float(u1.x << 16);
      acc[1] += aw1 * __uint_as_float(u1.x & 0xFFFF0000u);
      acc[2] += aw1 * __uint_as_float(u1.y << 16);
      acc[3] += aw1 * __uint_as_float(u1.y & 0xFFFF0000u);
      acc[4] += aw1 * __uint_as_float(u1.z << 16);
      acc[5] += aw1 * __uint_as_float(u1.z & 0xFFFF0000u);
      acc[6] += aw1 * __uint_as_float(u1.w << 16);
      acc[7] += aw1 * __uint_as_float(u1.w & 0xFFFF0000u);
    }
    if (p < cnt) {
      int sn = lds_sn[p];
      float aw = lds_sh[head][p];
      uint4 u = *(const uint4*)&feat1h[(size_t)sn * 256 + hl * 8];
      acc[0] += aw * __uint_as_float(u.x << 16);
      acc[1] += aw * __uint_as_float(u.x & 0xFFFF0000u);
      acc[2] += aw * __uint_as_float(u.y << 16);
      acc[3] += aw * __uint_as_float(u.y & 0xFFFF0000u);
      acc[4] += aw * __uint_as_float(u.z << 16);
      acc[5] += aw * __uint_as_float(u.z & 0xFFFF0000u);
      acc[6] += aw * __uint_as_float(u.w << 16);
      acc[7] += aw * __uint_as_float(u.w & 0xFFFF0000u);
    }
    if (c0 + 256 < deg) __syncthreads();
  }
#pragma unroll
  for (int r = 0; r < 8; ++r) acc[r] += __shfl_down(acc[r], 32, 64);
#pragma unroll
  for (int s = 32; s > 0; s >>= 1) {
    es4.x += __shfl_down(es4.x, s, 64);
    es4.y += __shfl_down(es4.y, s, 64);
    es4.z += __shfl_down(es4.z, s, 64);
    es4.w += __shfl_down(es4.w, s, 64);
  }
  if (half == 0) {
    *(float4*)&ldsacc[w][hl * 8] = make_float4(acc[0], acc[1], acc[2], acc[3]);
    *(float4*)&ldsacc[w][hl * 8 + 4] = make_float4(acc[4], acc[5], acc[6], acc[7]);
  }
  if (lane == 0) *(float4*)&ldssum[w][0] = es4;  // lane0 = wave's denominator partial
  __syncthreads();

  float tot = ldsacc[0][t] + ldsacc[1][t] + ldsacc[2][t] + ldsacc[3][t];
  int h = t >> 6;
  float denom = ldssum[0][h] + ldssum[1][h] + ldssum[2][h] + ldssum[3][h];
  float val = tot / fmaxf(denom, 1e-9f);
  val = (val > 0.f) ? val : expm1f(val);  // ELU

  float elp = val * wa[t];
  float erp = val * wb[t];
#pragma unroll
  for (int s = 32; s > 0; s >>= 1) {
    elp += __shfl_down(elp, s, 64);
    erp += __shfl_down(erp, s, 64);
  }
  if (lane == 0) {
    ldse[w] = elp;
    ldsr[w] = erp;
  }
  float vhi = __shfl_down(val, 1, 64);
  if (!(t & 1)) *(unsigned*)&h2h[(size_t)n * 256 + t] = f2bf(val) | (f2bf(vhi) << 16);
  __syncthreads();
  if (t == 0) {
    el2[n] = ldse[0] + ldse[1] + ldse[2] + ldse[3];
    er2[n] = ldsr[0] + ldsr[1] + ldsr[2] + ldsr[3];
  }
}

// ---------------- Layer 2 GEMM (MFMA bf16) + layer-2 edge scores ----------------
// Blocks [0,GB2): feat2ph(bf16, 48-padded) = h2h @ W2. Blocks [GB2,GB2+1250):
// edge-parallel exp-scores for layer 2 (fills the CUs the 157 GEMM tiles leave idle).
__global__ __launch_bounds__(256) void gemm2_kernel(
    const unsigned short* __restrict__ h2h, const unsigned short* __restrict__ W2f,
    unsigned short* __restrict__ feat2ph, const int* __restrict__ src_csr,
    const int* __restrict__ dst_csr, const float* __restrict__ el2,
    const float* __restrict__ er2, float* __restrict__ score2) {
  int t = threadIdx.x;
  if (blockIdx.x >= GB2) {  // ---- score path ----
    int i = (blockIdx.x - GB2) * 256 + t;
    if (i < N_EDGES) score2[i] = lrelu_exp(el2[src_csr[i]] + er2[dst_csr[i]]);
    return;
  }

  __shared__ __align__(16) char smem[32768 + 24576];
  unsigned short* ldsA = (unsigned short*)smem;            // 32 KB
  unsigned short* ldsB = (unsigned short*)(smem + 32768);  // 24 KB
  float* ldsC = (float*)(smem + 32768);                    // 12 KB (reuse B)

  int n0 = blockIdx.x * 64;
  int lane = t & 63;
  int w = t >> 6;
  int quad = lane >> 4;

#pragma unroll
  for (int i = 0; i < 8; ++i) {
    int idx = i * 256 + t;  // 0..2047 uint4s
    int m = idx >> 5;
    int kb = idx & 31;
    uint4 u = make_uint4(0, 0, 0, 0);
    if (n0 + m < N_NODES) u = ((const uint4*)(h2h + (size_t)(n0 + m) * 256))[kb];
    *(uint4*)&ldsA[m * 256 + ((kb ^ (m & 7)) << 3)] = u;
  }
  const uint4* Bg = (const uint4*)W2f;
#pragma unroll
  for (int i = 0; i < 6; ++i) ((uint4*)ldsB)[i * 256 + t] = Bg[i * 256 + t];
  __syncthreads();

  f32x4 acc[3];
#pragma unroll
  for (int nt = 0; nt < 3; ++nt) acc[nt] = 0.f;

#pragma unroll
  for (int ks = 0; ks < 8; ++ks) {
    int m = w * 16 + (lane & 15);
    int kb = ks * 4 + quad;
    bf16x8 af = *(const bf16x8*)&ldsA[m * 256 + ((kb ^ (m & 7)) << 3)];
#pragma unroll
    for (int nt = 0; nt < 3; ++nt) {
      bf16x8 bf = *(const bf16x8*)&ldsB[((nt * 8 + ks) * 64 + lane) * 8];
      acc[nt] = __builtin_amdgcn_mfma_f32_16x16x32_bf16(af, bf, acc[nt], 0, 0, 0);
    }
  }
  __syncthreads();  // all B reads done before C overwrites

#pragma unroll
  for (int nt = 0; nt < 3; ++nt)
#pragma unroll
    for (int r = 0; r < 4; ++r)
      ldsC[(w * 16 + quad * 4 + r) * 48 + nt * 16 + (lane & 15)] = acc[nt][r];
  __syncthreads();

#pragma unroll
  for (int i = 0; i < 6; ++i) {
    int idx = i * 256 + t;  // 0..1535
    int row = idx / 24;
    int c2 = idx - row * 24;
    int grow = n0 + row;
    if (grow < N_NODES) {
      unsigned u = f2bf(ldsC[row * 48 + c2 * 2]) | (f2bf(ldsC[row * 48 + c2 * 2 + 1]) << 16);
      ((unsigned*)feat2ph)[(size_t)grow * 24 + c2] = u;
    }
  }
}

// ---------------- Layer 2 aggregate + log_softmax (streaming scores) ----------------
__global__ __launch_bounds__(256) void agg2_kernel(
    const int* __restrict__ src_csr, const int* __restrict__ offsets,
    const unsigned short* __restrict__ feat2ph, const float* __restrict__ score2,
    float* __restrict__ out) {
  __shared__ float lds_s[256];
  __shared__ int lds_sn[256];
  __shared__ float ldsacc[4][48];
  __shared__ float ldssum[4];
  int n = blockIdx.x;
  int t = threadIdx.x;
  int w = t >> 6;
  int lane = t & 63;
  int half = lane >> 5;
  int hl = lane & 31;
  int off = offsets[n];
  int deg = offsets[n + 1] - off;

  float a0 = 0.f, a1 = 0.f;
  float es = 0.f;
  for (int c0 = 0; c0 < deg; c0 += 256) {
    int cnt = min(256, deg - c0);
    if (t < cnt) {
      lds_sn[t] = src_csr[off + c0 + t];
      float s = score2[off + c0 + t];
      lds_s[t] = s;
      es += s;
    }
    __syncthreads();
    int p = w * 2 + half;
    for (; p + 8 < cnt; p += 16) {
      int sn0 = lds_sn[p];
      int sn1 = lds_sn[p + 8];
      float s0 = lds_s[p];
      float s1 = lds_s[p + 8];
      if (hl < 24) {
        unsigned u0 = ((const unsigned*)feat2ph)[(size_t)sn0 * 24 + hl];
        unsigned u1 = ((const unsigned*)feat2ph)[(size_t)sn1 * 24 + hl];
        a0 += s0 * __uint_as_float(u0 << 16);
        a1 += s0 * __uint_as_float(u0 & 0xFFFF0000u);
        a0 += s1 * __uint_as_float(u1 << 16);
        a1 += s1 * __uint_as_float(u1 & 0xFFFF0000u);
      }
    }
    if (p < cnt) {
      int sn = lds_sn[p];
      float s = lds_s[p];
      if (hl < 24) {
        unsigned u = ((const unsigned*)feat2ph)[(size_t)sn * 24 + hl];
        a0 += s * __uint_as_float(u << 16);
        a1 += s * __uint_as_float(u & 0xFFFF0000u);
      }
    }
    if (c0 + 256 < deg) __syncthreads();
  }
  a0 += __shfl_down(a0, 32, 64);
  a1 += __shfl_down(a1, 32, 64);
#pragma unroll
  for (int s = 32; s > 0; s >>= 1) es += __shfl_down(es, s, 64);
  if (half == 0 && hl < 24) {
    ldsacc[w][hl * 2] = a0;
    ldsacc[w][hl * 2 + 1] = a1;
  }
  if (lane == 0) ldssum[w] = es;  // lane0 = wave's denominator partial
  __syncthreads();

  if (t < 64) {
    float denom = ldssum[0] + ldssum[1] + ldssum[2] + ldssum[3];
    float inv = 1.f / fmaxf(denom, 1e-9f);
    float logits = 0.f;
    if (t < OUT_FEATS)
      logits = (ldsacc[0][t] + ldsacc[1][t] + ldsacc[2][t] + ldsacc[3][t]) * inv;
    float v = (t < OUT_FEATS) ? logits : -INFINITY;
    float mx = wave_reduce_max(v);
    float ex = (t < OUT_FEATS) ? expf(logits - mx) : 0.f;
    float s = wave_reduce_sum(ex);
    if (t < OUT_FEATS) out[n * OUT_FEATS + t] = logits - mx - logf(s);
  }
}

extern "C" void kernel_launch(void* const* d_in, const int* in_sizes, int n_in,
                              void* d_out, int out_size, void* d_ws, size_t ws_size,
                              hipStream_t stream) {
  const float* features = (const float*)d_in[0];
  const int* src = (const int*)d_in[1];
  const int* dst = (const int*)d_in[2];
  const float* W1 = (const float*)d_in[3];
  const float* al1 = (const float*)d_in[4];
  const float* ar1 = (const float*)d_in[5];
  const float* W2 = (const float*)d_in[6];
  const float* al2 = (const float*)d_in[7];
  const float* ar2 = (const float*)d_in[8];
  float* out = (float*)d_out;

  char* ws = (char*)d_ws;
  size_t o = 0;
  auto alloc = [&](size_t bytes) {
    void* p = ws + o;
    o = (o + bytes + 255) & ~(size_t)255;
    return p;
  };
  unsigned short* feat1h = (unsigned short*)alloc((size_t)N_NODES * 256 * 2);
  unsigned short* h2h = (unsigned short*)alloc((size_t)N_NODES * 256 * 2);
  float* el1 = (float*)alloc((size_t)N_NODES * 4 * 4);
  float* er1 = (float*)alloc((size_t)N_NODES * 4 * 4);
  unsigned short* feat2ph = (unsigned short*)alloc((size_t)N_NODES * 48 * 2);
  float* el2v = (float*)alloc((size_t)N_NODES * 4);
  float* er2v = (float*)alloc((size_t)N_NODES * 4);
  unsigned short* W1f = (unsigned short*)alloc((size_t)256 * 256 * 2);
  unsigned short* W2f = (unsigned short*)alloc((size_t)256 * 48 * 2);
  float* wa = (float*)alloc(256 * 4);
  float* wb = (float*)alloc(256 * 4);
  int* deg = (int*)alloc((size_t)N_NODES * 4);
  int* cursor = (int*)alloc((size_t)N_NODES * 4);
  int* offsets = (int*)alloc((size_t)(N_NODES + 1) * 4);
  int* src_csr = (int*)alloc((size_t)N_EDGES * 4);
  int* dst_csr = (int*)alloc((size_t)N_EDGES * 4);
  float* score1 = (float*)alloc((size_t)N_EDGES * 4 * 4);
  float* score2 = (float*)alloc((size_t)N_EDGES * 4);

  hipMemsetAsync(deg, 0, (size_t)N_NODES * 4, stream);

  prep_kernel<<<1555, 256, 0, stream>>>(dst, deg, W1, W1f, W2, W2f, al2, ar2, wa, wb);
  gemm1_scan_kernel<<<314, 256, 0, stream>>>(features, W1f, al1, ar1, feat1h, el1, er1, deg,
                                             offsets, cursor);
  fill_kernel<<<(N_EDGES + 255) / 256, 256, 0, stream>>>(src, dst, cursor, src_csr, dst_csr,
                                                         el1, er1, score1);
  agg1_kernel<<<N_NODES, 256, 0, stream>>>(src_csr, offsets, feat1h, score1, wa, wb, h2h,
                                           el2v, er2v);
  gemm2_kernel<<<GB2 + (N_EDGES + 255) / 256, 256, 0, stream>>>(h2h, W2f, feat2ph, src_csr,
                                                                dst_csr, el2v, er2v, score2);
  agg2_kernel<<<N_NODES, 256, 0, stream>>>(src_csr, offsets, feat2ph, score2, out);
}

// Round 2
// 191.828 us; speedup vs baseline: 1.0451x; 1.0451x over previous
//
#include <hip/hip_runtime.h>
#include <math.h>

#define N_NODES 10000
#define N_EDGES 320000
#define IN_FEATS 256
#define N_HEADS 4
#define N_UNITS 64
#define OUT_FEATS 47
#define NEG_SLOPE 0.2f

typedef __attribute__((ext_vector_type(8))) short bf16x8;
typedef __attribute__((ext_vector_type(4))) float f32x4;

__device__ __forceinline__ float wave_reduce_sum(float v) {
#pragma unroll
  for (int s = 32; s > 0; s >>= 1) v += __shfl_down(v, s, 64);
  return __shfl(v, 0, 64);
}
__device__ __forceinline__ float wave_reduce_max(float v) {
#pragma unroll
  for (int s = 32; s > 0; s >>= 1) v = fmaxf(v, __shfl_down(v, s, 64));
  return __shfl(v, 0, 64);
}

__device__ __forceinline__ float lrelu_exp(float s) {
  s = (s > 0.f) ? s : NEG_SLOPE * s;
  return expf(s);
}

// fp32 -> bf16 round-to-nearest-even
__device__ __forceinline__ unsigned f2bf(float f) {
  unsigned u = __float_as_uint(f);
  return (u + 0x7FFFu + ((u >> 16) & 1u)) >> 16;
}

// ---------------- fused prep: deg count + W1/W2 packing + wa/wb ----------------
__global__ __launch_bounds__(256) void prep_kernel(
    const int* __restrict__ dst, int* __restrict__ deg,
    const float* __restrict__ W1, unsigned short* __restrict__ W1f,
    const float* __restrict__ W2, unsigned short* __restrict__ W2f,
    const float* __restrict__ al2, const float* __restrict__ ar2,
    float* __restrict__ wa, float* __restrict__ wb) {
  int b = blockIdx.x;
  int t = threadIdx.x;
  if (b < 1250) {
    int e = b * 256 + t;
    if (e < N_EDGES) atomicAdd(&deg[dst[e]], 1);
  } else if (b < 1250 + 256) {
    int o = (b - 1250) * 256 + t;  // 0..65535
    int j = o & 7;
    int lane = (o >> 3) & 63;
    int r = o >> 9;
    int ks = r & 7;
    int ntg = r >> 3;
    int k = ks * 32 + (lane >> 4) * 8 + j;
    int n = ntg * 16 + (lane & 15);
    W1f[o] = (unsigned short)f2bf(W1[k * 256 + n]);
  } else if (b < 1554) {
    int o = (b - 1506) * 256 + t;  // 0..12287
    int j = o & 7;
    int lane = (o >> 3) & 63;
    int r = o >> 9;  // 0..23
    int ks = r & 7;
    int ntg = r >> 3;  // 0..2
    int k = ks * 32 + (lane >> 4) * 8 + j;
    int n = ntg * 16 + (lane & 15);
    W2f[o] = (n < OUT_FEATS) ? (unsigned short)f2bf(W2[k * OUT_FEATS + n]) : 0;
  } else {
    float a = 0.f, r = 0.f;
    for (int c = 0; c < OUT_FEATS; ++c) {
      float w = W2[t * OUT_FEATS + c];
      a += w * al2[c];
      r += w * ar2[c];
    }
    wa[t] = a;
    wb[t] = r;
  }
}

// CSR fill: src ids only (scores computed inline in agg kernels).
__global__ void fill_kernel(const int* __restrict__ src, const int* __restrict__ dst,
                            int* __restrict__ cursor, int* __restrict__ src_csr) {
  int e = blockIdx.x * blockDim.x + threadIdx.x;
  if (e >= N_EDGES) return;
  int p = atomicAdd(&cursor[dst[e]], 1);
  src_csr[p] = src[e];
}

// ---------------- Layer 1 GEMM (MFMA bf16) + fused scan (block 313) ----------------
__global__ __launch_bounds__(256) void gemm1_scan_kernel(
    const float* __restrict__ features, const unsigned short* __restrict__ W1f,
    const float* __restrict__ al1, const float* __restrict__ ar1,
    unsigned short* __restrict__ feat1h, float* __restrict__ el1, float* __restrict__ er1,
    const int* __restrict__ deg, int* __restrict__ offsets, int* __restrict__ cursor) {
  __shared__ __align__(16) char smem[49152];
  int t = threadIdx.x;

  if (blockIdx.x == 313) {  // ---- scan path ----
    int* partial = (int*)smem;
    const int chunk = (N_NODES + 255) / 256;  // 40
    int start = t * chunk;
    int end = min(start + chunk, N_NODES);
    int sum = 0;
    for (int i = start; i < end; ++i) sum += deg[i];
    partial[t] = sum;
    __syncthreads();
    for (int s = 1; s < 256; s <<= 1) {
      int v = (t >= s) ? partial[t - s] : 0;
      __syncthreads();
      partial[t] += v;
      __syncthreads();
    }
    int base = (t == 0) ? 0 : partial[t - 1];
    for (int i = start; i < end; ++i) {
      offsets[i] = base;
      cursor[i] = base;
      base += deg[i];
    }
    if (t == 0) offsets[N_NODES] = partial[255];
    return;
  }

  // ---- GEMM path ----
  unsigned short* ldsA = (unsigned short*)smem;                    // 16 KB
  unsigned short* ldsBbuf[2] = {(unsigned short*)(smem + 16384),
                                (unsigned short*)(smem + 32768)};  // 2 x 16 KB
  float* ldsC = (float*)(smem + 16384);                            // 32 KB (reuse B)

  int n0 = blockIdx.x * 32;
  int lane = t & 63;
  int w = t >> 6;
  int quad = lane >> 4;

  const float4* feat4 = (const float4*)features;
#pragma unroll
  for (int i = 0; i < 8; ++i) {
    int idx = i * 256 + t;
    int m = idx >> 6;
    int kb4 = idx & 63;
    float4 f = make_float4(0.f, 0.f, 0.f, 0.f);
    if (n0 + m < N_NODES) f = feat4[(size_t)(n0 + m) * 64 + kb4];
    unsigned u0 = f2bf(f.x) | (f2bf(f.y) << 16);
    unsigned u1 = f2bf(f.z) | (f2bf(f.w) << 16);
    int kb = kb4 >> 1;
    int di = m * 256 + ((kb ^ (m & 7)) << 3) + ((kb4 & 1) << 2);
    *(uint2*)&ldsA[di] = make_uint2(u0, u1);
  }

  const uint4* W1f4 = (const uint4*)W1f;
  uint4 pb[4];
#pragma unroll
  for (int it = 0; it < 4; ++it) {
    int ci = it * 256 + t;
    pb[it] = W1f4[((ci >> 6) * 8 + 0) * 64 + (ci & 63)];
  }
#pragma unroll
  for (int it = 0; it < 4; ++it) ((uint4*)ldsBbuf[0])[it * 256 + t] = pb[it];
  __syncthreads();

  f32x4 acc[2][4];
#pragma unroll
  for (int mt = 0; mt < 2; ++mt)
#pragma unroll
    for (int nt = 0; nt < 4; ++nt) acc[mt][nt] = 0.f;

  for (int ks = 0; ks < 8; ++ks) {
    if (ks < 7) {
#pragma unroll
      for (int it = 0; it < 4; ++it) {
        int ci = it * 256 + t;
        pb[it] = W1f4[((ci >> 6) * 8 + ks + 1) * 64 + (ci & 63)];
      }
    }
    unsigned short* B = ldsBbuf[ks & 1];
    bf16x8 af[2];
#pragma unroll
    for (int mt = 0; mt < 2; ++mt) {
      int m = mt * 16 + (lane & 15);
      int kb = ks * 4 + quad;
      af[mt] = *(const bf16x8*)&ldsA[m * 256 + ((kb ^ (m & 7)) << 3)];
    }
#pragma unroll
    for (int nt = 0; nt < 4; ++nt) {
      bf16x8 bf = *(const bf16x8*)&B[((w * 4 + nt) * 64 + lane) * 8];
#pragma unroll
      for (int mt = 0; mt < 2; ++mt)
        acc[mt][nt] = __builtin_amdgcn_mfma_f32_16x16x32_bf16(af[mt], bf, acc[mt][nt], 0, 0, 0);
    }
    if (ks < 7) {
      unsigned short* Bn = ldsBbuf[(ks + 1) & 1];
#pragma unroll
      for (int it = 0; it < 4; ++it) ((uint4*)Bn)[it * 256 + t] = pb[it];
    }
    __syncthreads();
  }

#pragma unroll
  for (int mt = 0; mt < 2; ++mt)
#pragma unroll
    for (int nt = 0; nt < 4; ++nt)
#pragma unroll
      for (int r = 0; r < 4; ++r)
        ldsC[(mt * 16 + quad * 4 + r) * 256 + w * 64 + nt * 16 + (lane & 15)] = acc[mt][nt][r];
  __syncthreads();

  int c = lane * 4;
  int r0 = w * 8;
  float4 alv = ((const float4*)al1)[lane];
  float4 arv = ((const float4*)ar1)[lane];
#pragma unroll
  for (int i = 0; i < 8; ++i) {
    int rl = r0 + i;
    int row = n0 + rl;
    float4 a = *(const float4*)&ldsC[rl * 256 + c];
    bool valid = row < N_NODES;
    if (valid) {
      unsigned p0 = f2bf(a.x) | (f2bf(a.y) << 16);
      unsigned p1 = f2bf(a.z) | (f2bf(a.w) << 16);
      *(uint2*)&feat1h[(size_t)row * 256 + c] = make_uint2(p0, p1);
    }
    float el = a.x * alv.x + a.y * alv.y + a.z * alv.z + a.w * alv.w;
    float er = a.x * arv.x + a.y * arv.y + a.z * arv.z + a.w * arv.w;
#pragma unroll
    for (int s = 8; s > 0; s >>= 1) {
      el += __shfl_down(el, s, 16);
      er += __shfl_down(er, s, 16);
    }
    if ((lane & 15) == 0 && valid) {
      el1[row * 4 + (lane >> 4)] = el;
      er1[row * 4 + (lane >> 4)] = er;
    }
  }
}

// ---------------- Layer 1 aggregate: one WAVE per node, no LDS, no barriers -------
// Half-wave (32 lanes x 16B = full 512B bf16 row) per edge; halves take alternating
// edges; 2 edges in flight per half. All reductions via shuffles.
__global__ __launch_bounds__(256) void agg1_kernel(
    const int* __restrict__ src_csr, const int* __restrict__ offsets,
    const unsigned short* __restrict__ feat1h, const float* __restrict__ el1,
    const float* __restrict__ er1, const float* __restrict__ wa,
    const float* __restrict__ wb, unsigned short* __restrict__ h2h,
    float* __restrict__ el2, float* __restrict__ er2) {
  int t = threadIdx.x;
  int w = t >> 6;
  int n = blockIdx.x * 4 + w;
  if (n >= N_NODES) return;
  int lane = t & 63;
  int half = lane >> 5;
  int hl = lane & 31;
  int head = hl >> 3;
  int off = offsets[n];
  int deg = offsets[n + 1] - off;
  float ern = er1[n * 4 + head];
  const int* sc = src_csr + off;

  float acc[8];
#pragma unroll
  for (int r = 0; r < 8; ++r) acc[r] = 0.f;
  float esum = 0.f;

  int p = half;
  for (; p + 2 < deg; p += 4) {
    int sn0 = sc[p];
    int sn1 = sc[p + 2];
    float e0 = el1[sn0 * 4 + head];
    float e1 = el1[sn1 * 4 + head];
    uint4 u0 = *(const uint4*)&feat1h[(size_t)sn0 * 256 + hl * 8];
    uint4 u1 = *(const uint4*)&feat1h[(size_t)sn1 * 256 + hl * 8];
    float aw0 = lrelu_exp(e0 + ern);
    float aw1 = lrelu_exp(e1 + ern);
    acc[0] += aw0 * __uint_as_float(u0.x << 16) + aw1 * __uint_as_float(u1.x << 16);
    acc[1] += aw0 * __uint_as_float(u0.x & 0xFFFF0000u) + aw1 * __uint_as_float(u1.x & 0xFFFF0000u);
    acc[2] += aw0 * __uint_as_float(u0.y << 16) + aw1 * __uint_as_float(u1.y << 16);
    acc[3] += aw0 * __uint_as_float(u0.y & 0xFFFF0000u) + aw1 * __uint_as_float(u1.y & 0xFFFF0000u);
    acc[4] += aw0 * __uint_as_float(u0.z << 16) + aw1 * __uint_as_float(u1.z << 16);
    acc[5] += aw0 * __uint_as_float(u0.z & 0xFFFF0000u) + aw1 * __uint_as_float(u1.z & 0xFFFF0000u);
    acc[6] += aw0 * __uint_as_float(u0.w << 16) + aw1 * __uint_as_float(u1.w << 16);
    acc[7] += aw0 * __uint_as_float(u0.w & 0xFFFF0000u) + aw1 * __uint_as_float(u1.w & 0xFFFF0000u);
    esum += aw0 + aw1;
  }
  if (p < deg) {
    int sn = sc[p];
    float e = el1[sn * 4 + head];
    uint4 u = *(const uint4*)&feat1h[(size_t)sn * 256 + hl * 8];
    float aw = lrelu_exp(e + ern);
    acc[0] += aw * __uint_as_float(u.x << 16);
    acc[1] += aw * __uint_as_float(u.x & 0xFFFF0000u);
    acc[2] += aw * __uint_as_float(u.y << 16);
    acc[3] += aw * __uint_as_float(u.y & 0xFFFF0000u);
    acc[4] += aw * __uint_as_float(u.z << 16);
    acc[5] += aw * __uint_as_float(u.z & 0xFFFF0000u);
    acc[6] += aw * __uint_as_float(u.w << 16);
    acc[7] += aw * __uint_as_float(u.w & 0xFFFF0000u);
    esum += aw;
  }

  // combine odd/even halves: half0 lanes end with full sums
#pragma unroll
  for (int r = 0; r < 8; ++r) acc[r] += __shfl_down(acc[r], 32, 64);
  esum += __shfl_down(esum, 32, 64);
  float inv = 1.f / fmaxf(esum, 1e-9f);

  float4 wa0 = ((const float4*)wa)[hl * 2];
  float4 wa1 = ((const float4*)wa)[hl * 2 + 1];
  float4 wb0 = ((const float4*)wb)[hl * 2];
  float4 wb1 = ((const float4*)wb)[hl * 2 + 1];
  float v[8];
#pragma unroll
  for (int j = 0; j < 8; ++j) {
    float x = acc[j] * inv;
    v[j] = (x > 0.f) ? x : expm1f(x);  // ELU
  }
  float elp = v[0] * wa0.x + v[1] * wa0.y + v[2] * wa0.z + v[3] * wa0.w +
              v[4] * wa1.x + v[5] * wa1.y + v[6] * wa1.z + v[7] * wa1.w;
  float erp = v[0] * wb0.x + v[1] * wb0.y + v[2] * wb0.z + v[3] * wb0.w +
              v[4] * wb1.x + v[5] * wb1.y + v[6] * wb1.z + v[7] * wb1.w;
  if (half) {  // half1 holds garbage partials; zero before wave reduce
    elp = 0.f;
    erp = 0.f;
  }
  if (half == 0) {
    uint4 pk;
    pk.x = f2bf(v[0]) | (f2bf(v[1]) << 16);
    pk.y = f2bf(v[2]) | (f2bf(v[3]) << 16);
    pk.z = f2bf(v[4]) | (f2bf(v[5]) << 16);
    pk.w = f2bf(v[6]) | (f2bf(v[7]) << 16);
    *(uint4*)&h2h[(size_t)n * 256 + hl * 8] = pk;
  }
#pragma unroll
  for (int s = 32; s > 0; s >>= 1) {
    elp += __shfl_down(elp, s, 64);
    erp += __shfl_down(erp, s, 64);
  }
  if (lane == 0) {
    el2[n] = elp;
    er2[n] = erp;
  }
}

// ---------------- Layer 2 GEMM (MFMA bf16): feat2ph(bf16, 48-padded) = h2h @ W2 ------
__global__ __launch_bounds__(256) void gemm2_kernel(
    const unsigned short* __restrict__ h2h, const unsigned short* __restrict__ W2f,
    unsigned short* __restrict__ feat2ph) {
  __shared__ __align__(16) char smem[32768 + 24576];
  unsigned short* ldsA = (unsigned short*)smem;            // 32 KB
  unsigned short* ldsB = (unsigned short*)(smem + 32768);  // 24 KB
  float* ldsC = (float*)(smem + 32768);                    // 12 KB (reuse B)

  int t = threadIdx.x;
  int n0 = blockIdx.x * 64;
  int lane = t & 63;
  int w = t >> 6;
  int quad = lane >> 4;

#pragma unroll
  for (int i = 0; i < 8; ++i) {
    int idx = i * 256 + t;  // 0..2047 uint4s
    int m = idx >> 5;
    int kb = idx & 31;
    uint4 u = make_uint4(0, 0, 0, 0);
    if (n0 + m < N_NODES) u = ((const uint4*)(h2h + (size_t)(n0 + m) * 256))[kb];
    *(uint4*)&ldsA[m * 256 + ((kb ^ (m & 7)) << 3)] = u;
  }
  const uint4* Bg = (const uint4*)W2f;
#pragma unroll
  for (int i = 0; i < 6; ++i) ((uint4*)ldsB)[i * 256 + t] = Bg[i * 256 + t];
  __syncthreads();

  f32x4 acc[3];
#pragma unroll
  for (int nt = 0; nt < 3; ++nt) acc[nt] = 0.f;

#pragma unroll
  for (int ks = 0; ks < 8; ++ks) {
    int m = w * 16 + (lane & 15);
    int kb = ks * 4 + quad;
    bf16x8 af = *(const bf16x8*)&ldsA[m * 256 + ((kb ^ (m & 7)) << 3)];
#pragma unroll
    for (int nt = 0; nt < 3; ++nt) {
      bf16x8 bf = *(const bf16x8*)&ldsB[((nt * 8 + ks) * 64 + lane) * 8];
      acc[nt] = __builtin_amdgcn_mfma_f32_16x16x32_bf16(af, bf, acc[nt], 0, 0, 0);
    }
  }
  __syncthreads();  // all B reads done before C overwrites

#pragma unroll
  for (int nt = 0; nt < 3; ++nt)
#pragma unroll
    for (int r = 0; r < 4; ++r)
      ldsC[(w * 16 + quad * 4 + r) * 48 + nt * 16 + (lane & 15)] = acc[nt][r];
  __syncthreads();

#pragma unroll
  for (int i = 0; i < 6; ++i) {
    int idx = i * 256 + t;  // 0..1535
    int row = idx / 24;
    int c2 = idx - row * 24;
    int grow = n0 + row;
    if (grow < N_NODES) {
      unsigned u = f2bf(ldsC[row * 48 + c2 * 2]) | (f2bf(ldsC[row * 48 + c2 * 2 + 1]) << 16);
      ((unsigned*)feat2ph)[(size_t)grow * 24 + c2] = u;
    }
  }
}

// ---------------- Layer 2 aggregate + log_softmax: one WAVE per node --------------
__global__ __launch_bounds__(256) void agg2_kernel(
    const int* __restrict__ src_csr, const int* __restrict__ offsets,
    const unsigned short* __restrict__ feat2ph, const float* __restrict__ el2,
    const float* __restrict__ er2, float* __restrict__ out) {
  int t = threadIdx.x;
  int w = t >> 6;
  int n = blockIdx.x * 4 + w;
  if (n >= N_NODES) return;
  int lane = t & 63;
  int half = lane >> 5;
  int hl = lane & 31;
  int off = offsets[n];
  int deg = offsets[n + 1] - off;
  float ern = er2[n];
  const int* sc = src_csr + off;
  const unsigned* f2 = (const unsigned*)feat2ph;
  bool act = hl < 24;

  float a0 = 0.f, a1 = 0.f, esum = 0.f;
  int p = half;
  for (; p + 2 < deg; p += 4) {
    int sn0 = sc[p];
    int sn1 = sc[p + 2];
    float e0 = el2[sn0];
    float e1 = el2[sn1];
    unsigned u0 = act ? f2[(size_t)sn0 * 24 + hl] : 0u;
    unsigned u1 = act ? f2[(size_t)sn1 * 24 + hl] : 0u;
    float aw0 = lrelu_exp(e0 + ern);
    float aw1 = lrelu_exp(e1 + ern);
    a0 += aw0 * __uint_as_float(u0 << 16) + aw1 * __uint_as_float(u1 << 16);
    a1 += aw0 * __uint_as_float(u0 & 0xFFFF0000u) + aw1 * __uint_as_float(u1 & 0xFFFF0000u);
    esum += aw0 + aw1;
  }
  if (p < deg) {
    int sn = sc[p];
    float e = el2[sn];
    unsigned u = act ? f2[(size_t)sn * 24 + hl] : 0u;
    float aw = lrelu_exp(e + ern);
    a0 += aw * __uint_as_float(u << 16);
    a1 += aw * __uint_as_float(u & 0xFFFF0000u);
    esum += aw;
  }

  a0 += __shfl_down(a0, 32, 64);
  a1 += __shfl_down(a1, 32, 64);
  esum += __shfl_down(esum, 32, 64);
  float inv = 1.f / fmaxf(esum, 1e-9f);
  int c0 = hl * 2;
  int c1 = hl * 2 + 1;
  bool v0 = (half == 0) && (c0 < OUT_FEATS);
  bool v1 = (half == 0) && (c1 < OUT_FEATS);
  float l0 = a0 * inv;
  float l1 = a1 * inv;
  float m = fmaxf(v0 ? l0 : -INFINITY, v1 ? l1 : -INFINITY);
  m = wave_reduce_max(m);
  float ex = (v0 ? expf(l0 - m) : 0.f) + (v1 ? expf(l1 - m) : 0.f);
  float s = wave_reduce_sum(ex);
  float ls = logf(s);
  if (v0) out[n * OUT_FEATS + c0] = l0 - m - ls;
  if (v1) out[n * OUT_FEATS + c1] = l1 - m - ls;
}

extern "C" void kernel_launch(void* const* d_in, const int* in_sizes, int n_in,
                              void* d_out, int out_size, void* d_ws, size_t ws_size,
                              hipStream_t stream) {
  const float* features = (const float*)d_in[0];
  const int* src = (const int*)d_in[1];
  const int* dst = (const int*)d_in[2];
  const float* W1 = (const float*)d_in[3];
  const float* al1 = (const float*)d_in[4];
  const float* ar1 = (const float*)d_in[5];
  const float* W2 = (const float*)d_in[6];
  const float* al2 = (const float*)d_in[7];
  const float* ar2 = (const float*)d_in[8];
  float* out = (float*)d_out;

  char* ws = (char*)d_ws;
  size_t o = 0;
  auto alloc = [&](size_t bytes) {
    void* p = ws + o;
    o = (o + bytes + 255) & ~(size_t)255;
    return p;
  };
  unsigned short* feat1h = (unsigned short*)alloc((size_t)N_NODES * 256 * 2);
  unsigned short* h2h = (unsigned short*)alloc((size_t)N_NODES * 256 * 2);
  float* el1 = (float*)alloc((size_t)N_NODES * 4 * 4);
  float* er1 = (float*)alloc((size_t)N_NODES * 4 * 4);
  unsigned short* feat2ph = (unsigned short*)alloc((size_t)N_NODES * 48 * 2);
  float* el2v = (float*)alloc((size_t)N_NODES * 4);
  float* er2v = (float*)alloc((size_t)N_NODES * 4);
  unsigned short* W1f = (unsigned short*)alloc((size_t)256 * 256 * 2);
  unsigned short* W2f = (unsigned short*)alloc((size_t)256 * 48 * 2);
  float* wa = (float*)alloc(256 * 4);
  float* wb = (float*)alloc(256 * 4);
  int* deg = (int*)alloc((size_t)N_NODES * 4);
  int* cursor = (int*)alloc((size_t)N_NODES * 4);
  int* offsets = (int*)alloc((size_t)(N_NODES + 1) * 4);
  int* src_csr = (int*)alloc((size_t)N_EDGES * 4);

  hipMemsetAsync(deg, 0, (size_t)N_NODES * 4, stream);

  prep_kernel<<<1555, 256, 0, stream>>>(dst, deg, W1, W1f, W2, W2f, al2, ar2, wa, wb);
  gemm1_scan_kernel<<<314, 256, 0, stream>>>(features, W1f, al1, ar1, feat1h, el1, er1, deg,
                                             offsets, cursor);
  fill_kernel<<<(N_EDGES + 255) / 256, 256, 0, stream>>>(src, dst, cursor, src_csr);
  agg1_kernel<<<(N_NODES + 3) / 4, 256, 0, stream>>>(src_csr, offsets, feat1h, el1, er1, wa,
                                                     wb, h2h, el2v, er2v);
  gemm2_kernel<<<(N_NODES + 63) / 64, 256, 0, stream>>>(h2h, W2f, feat2ph);
  agg2_kernel<<<(N_NODES + 3) / 4, 256, 0, stream>>>(src_csr, offsets, feat2ph, el2v, er2v,
                                                     out);
}